// Round 2
// baseline (337.064 us; speedup 1.0000x reference)
//
#include <hip/hip_runtime.h>
#include <stdint.h>

// CORDIV stochastic-computing divider — Round 14: identical resubmit of
// R13 (R12 + non-temporal output stores). R13's bench died on container
// acquisition ("MI355X container failed twice") — infra, not kernel.
//
// R12 baseline: 114us/dispatch. Counters: FETCH=128MB (half of the 256MB
// input already L3-resident across replays), WRITE=128MB, HBM 2.36 TB/s =
// 37% of achievable — not HBM-saturated. Limiter: output writeback
// evicting input lines from the 256MB Infinity Cache + read/write DRAM
// interleave. Output is write-once/never-read: mark stores non-temporal
// (global_store_dwordx4 ... nt, evict-first) so inputs stay L3-resident.
// Predicted: FETCH 131MB -> <40MB, dur 114 -> ~75-90us.
//
// Everything else unchanged from R12: CHUNK=1 double-buffer, 16KB LDS,
// 8 blocks/CU, grid 2048 zero-tail, never-drain vmcnt bookkeeping
// (nt store still enters the VMEM FIFO identically).

#define SC_T   16
#define BLOCK  256

typedef float v4f __attribute__((ext_vector_type(4)));
typedef const __attribute__((address_space(1))) void glb_void;
typedef __attribute__((address_space(3))) void lds_void;

// VMEM FIFO ops younger than plane-t's 2 DMAs at its wait point.
// Order: prologue [DMA0, DMA1]; iter t: [wait_t, store_t, DMA(t+2)].
//   t==0 : DMA(1)                 -> 2
//   1..14: store(t-1) + DMA(t+1)  -> 1+2 = 3
//   t==15: store(14)              -> 1
#define WAITN(t) (1 * ((t) >= 1) + 2 * ((t) + 1 < SC_T))

__global__ __launch_bounds__(BLOCK) void cordiv_kernel(
    const v4f*   __restrict__ dividend,
    const v4f*   __restrict__ divisor,
    const float* __restrict__ sr_init_f,   // [BUF_DEP, N] — lane-uniform rows
    const int*   __restrict__ rng_table,
    v4f*         __restrict__ out,
    int n4)   // N / 4 = 524288
{
    __shared__ v4f ldsD[2][BLOCK];
    __shared__ v4f ldsS[2][BLOCK];

    const int tid   = threadIdx.x;
    const int gid   = blockIdx.x * BLOCK + tid;
    const int wbase = tid & ~63;            // wave's slice base in block

    const size_t nElem = (size_t)n4 * 4;    // N

    // rng table (uniform) + sr rows (lane-uniform by semantic contract).
    int   r0 = rng_table[0];
    int   r1 = rng_table[1];
    int   r2 = rng_table[2];
    int   r3 = rng_table[3];
    float s0 = sr_init_f[0 * nElem];
    float s1 = sr_init_f[1 * nElem];
    float s2 = sr_init_f[2 * nElem];
    float s3 = sr_init_f[3 * nElem];
    // Pin: the compiler's waitcnt for these loads must land HERE, before
    // any DMA enters the VMEM FIFO (a later vmcnt(0) would drain the pipe).
    asm volatile("" : "+v"(r0), "+v"(r1), "+v"(r2), "+v"(r3),
                      "+v"(s0), "+v"(s1), "+v"(s2), "+v"(s3));
    const int rtab[4] = {r0, r1, r2, r3};

    v4f sr0 = {s0, s0, s0, s0};
    v4f sr1 = {s1, s1, s1, s1};
    v4f sr2 = {s2, s2, s2, s2};
    v4f sr3 = {s3, s3, s3, s3};

#define ISSUE(t) do {                                                     \
        __builtin_amdgcn_global_load_lds(                                 \
            (glb_void*)(dividend + (size_t)(t) * n4 + gid),               \
            (lds_void*)&ldsD[(t) & 1][wbase], 16, 0, 0);                  \
        __builtin_amdgcn_global_load_lds(                                 \
            (glb_void*)(divisor + (size_t)(t) * n4 + gid),               \
            (lds_void*)&ldsS[(t) & 1][wbase], 16, 0, 0);                  \
    } while (0)

    // Prologue: two planes in flight.
    ISSUE(0);
    ISSUE(1);

#pragma unroll
    for (int t = 0; t < SC_T; ++t) {
        // Wait for plane t's DMAs only; store(t-1) and plane t+1 in flight.
        asm volatile("s_waitcnt vmcnt(%c0)" :: "i"(WAITN(t)) : "memory");

        const int r = rtab[t & 3];

        const v4f dvd = ldsD[t & 1][tid];   // ds_read_b128, conflict-free
        const v4f dvs = ldsS[t & 1][tid];

        const v4f hq = (r == 0) ? sr0 : (r == 1) ? sr1
                     : (r == 2) ? sr2 : sr3;

        v4f q;
        q.x = (dvs.x == 1.0f) ? dvd.x : hq.x;
        q.y = (dvs.y == 1.0f) ? dvd.y : hq.y;
        q.z = (dvs.z == 1.0f) ? dvd.z : hq.z;
        q.w = (dvs.w == 1.0f) ? dvd.w : hq.w;

        // Non-temporal: output is write-once/never-read — don't let its
        // writeback evict the L3-resident input planes.
        __builtin_nontemporal_store(q, &out[(size_t)t * n4 + gid]);

        // Refill the buffer just consumed (program-order after the store
        // that consumed it -> no LDS overwrite race).
        if (t + 2 < SC_T) ISSUE(t + 2);

        sr3 = sr2; sr2 = sr1; sr1 = sr0; sr0 = q;
    }
#undef ISSUE
}

extern "C" void kernel_launch(void* const* d_in, const int* in_sizes, int n_in,
                              void* d_out, int out_size, void* d_ws, size_t ws_size,
                              hipStream_t stream) {
    const float* dividend = (const float*)d_in[0];   // [T, N]
    const float* divisor  = (const float*)d_in[1];   // [T, N]
    const float* sr_init  = (const float*)d_in[2];   // [BUF_DEP, N]
    const int*   rng      = (const int*)d_in[3];     // [4]
    float*       out      = (float*)d_out;           // [T, N]

    const int n  = in_sizes[0] / SC_T;   // N = 2^21
    const int n4 = n / 4;                // 524288

    const int grid = n4 / BLOCK;         // 2048 blocks = 8/CU, full residency

    cordiv_kernel<<<grid, BLOCK, 0, stream>>>(
        (const v4f*)dividend, (const v4f*)divisor,
        sr_init, rng, (v4f*)out, n4);
}

// Round 3
// 326.681 us; speedup vs baseline: 1.0318x; 1.0318x over previous
//
#include <hip/hip_runtime.h>
#include <stdint.h>

// CORDIV stochastic-computing divider — Round 15: exact revert to R12
// (known best: 327.8us session-best / 330.0us confirm; 114us/dispatch).
//
// R13/R14 nt-store experiment FALSIFIED: FETCH unchanged (131MB — nt does
// not protect input L3 residency on gfx950), dur 114->134us regression
// with identical HBM traffic. Mechanism: in-order vmcnt retirement puts
// DRAM-latency nt stores on the critical path of every later vmcnt(3)
// wait; default L2 write-back stores retire fast and never stall.
// Conclusion: output-eviction of the input working set is structural at
// HIP source level — no L2/L3 persistence control exists on this chip.
//
// R12 design (unchanged): CHUNK=1 double-buffer, 16KB LDS -> 8 blocks/CU
// (wave-cap bound, 32 waves/CU), grid 2048 = 8 x 256 CUs zero-tail,
// global_load_lds width-16 DMA staging, never-drain vmcnt bookkeeping
// (steady wait: 1 store + 2 next-plane DMAs in flight).

#define SC_T   16
#define BLOCK  256

typedef float v4f __attribute__((ext_vector_type(4)));
typedef const __attribute__((address_space(1))) void glb_void;
typedef __attribute__((address_space(3))) void lds_void;

// VMEM FIFO ops younger than plane-t's 2 DMAs at its wait point.
// Order: prologue [DMA0, DMA1]; iter t: [wait_t, store_t, DMA(t+2)].
//   t==0 : DMA(1)                 -> 2
//   1..14: store(t-1) + DMA(t+1)  -> 1+2 = 3
//   t==15: store(14)              -> 1
#define WAITN(t) (1 * ((t) >= 1) + 2 * ((t) + 1 < SC_T))

__global__ __launch_bounds__(BLOCK) void cordiv_kernel(
    const v4f*   __restrict__ dividend,
    const v4f*   __restrict__ divisor,
    const float* __restrict__ sr_init_f,   // [BUF_DEP, N] — lane-uniform rows
    const int*   __restrict__ rng_table,
    v4f*         __restrict__ out,
    int n4)   // N / 4 = 524288
{
    __shared__ v4f ldsD[2][BLOCK];
    __shared__ v4f ldsS[2][BLOCK];

    const int tid   = threadIdx.x;
    const int gid   = blockIdx.x * BLOCK + tid;
    const int wbase = tid & ~63;            // wave's slice base in block

    const size_t nElem = (size_t)n4 * 4;    // N

    // rng table (uniform) + sr rows (lane-uniform by semantic contract).
    int   r0 = rng_table[0];
    int   r1 = rng_table[1];
    int   r2 = rng_table[2];
    int   r3 = rng_table[3];
    float s0 = sr_init_f[0 * nElem];
    float s1 = sr_init_f[1 * nElem];
    float s2 = sr_init_f[2 * nElem];
    float s3 = sr_init_f[3 * nElem];
    // Pin: the compiler's waitcnt for these loads must land HERE, before
    // any DMA enters the VMEM FIFO (a later vmcnt(0) would drain the pipe).
    asm volatile("" : "+v"(r0), "+v"(r1), "+v"(r2), "+v"(r3),
                      "+v"(s0), "+v"(s1), "+v"(s2), "+v"(s3));
    const int rtab[4] = {r0, r1, r2, r3};

    v4f sr0 = {s0, s0, s0, s0};
    v4f sr1 = {s1, s1, s1, s1};
    v4f sr2 = {s2, s2, s2, s2};
    v4f sr3 = {s3, s3, s3, s3};

#define ISSUE(t) do {                                                     \
        __builtin_amdgcn_global_load_lds(                                 \
            (glb_void*)(dividend + (size_t)(t) * n4 + gid),               \
            (lds_void*)&ldsD[(t) & 1][wbase], 16, 0, 0);                  \
        __builtin_amdgcn_global_load_lds(                                 \
            (glb_void*)(divisor + (size_t)(t) * n4 + gid),               \
            (lds_void*)&ldsS[(t) & 1][wbase], 16, 0, 0);                  \
    } while (0)

    // Prologue: two planes in flight.
    ISSUE(0);
    ISSUE(1);

#pragma unroll
    for (int t = 0; t < SC_T; ++t) {
        // Wait for plane t's DMAs only; store(t-1) and plane t+1 in flight.
        asm volatile("s_waitcnt vmcnt(%c0)" :: "i"(WAITN(t)) : "memory");

        const int r = rtab[t & 3];

        const v4f dvd = ldsD[t & 1][tid];   // ds_read_b128, conflict-free
        const v4f dvs = ldsS[t & 1][tid];

        const v4f hq = (r == 0) ? sr0 : (r == 1) ? sr1
                     : (r == 2) ? sr2 : sr3;

        v4f q;
        q.x = (dvs.x == 1.0f) ? dvd.x : hq.x;
        q.y = (dvs.y == 1.0f) ? dvd.y : hq.y;
        q.z = (dvs.z == 1.0f) ? dvd.z : hq.z;
        q.w = (dvs.w == 1.0f) ? dvd.w : hq.w;

        out[(size_t)t * n4 + gid] = q;

        // Refill the buffer just consumed (program-order after the store
        // that consumed it -> no LDS overwrite race).
        if (t + 2 < SC_T) ISSUE(t + 2);

        sr3 = sr2; sr2 = sr1; sr1 = sr0; sr0 = q;
    }
#undef ISSUE
}

extern "C" void kernel_launch(void* const* d_in, const int* in_sizes, int n_in,
                              void* d_out, int out_size, void* d_ws, size_t ws_size,
                              hipStream_t stream) {
    const float* dividend = (const float*)d_in[0];   // [T, N]
    const float* divisor  = (const float*)d_in[1];   // [T, N]
    const float* sr_init  = (const float*)d_in[2];   // [BUF_DEP, N]
    const int*   rng      = (const int*)d_in[3];     // [4]
    float*       out      = (float*)d_out;           // [T, N]

    const int n  = in_sizes[0] / SC_T;   // N = 2^21
    const int n4 = n / 4;                // 524288

    const int grid = n4 / BLOCK;         // 2048 blocks = 8/CU, full residency

    cordiv_kernel<<<grid, BLOCK, 0, stream>>>(
        (const v4f*)dividend, (const v4f*)divisor,
        sr_init, rng, (v4f*)out, n4);
}